// Round 8
// baseline (1430.169 us; speedup 1.0000x reference)
//
#include <hip/hip_runtime.h>

// psRNN round 8: r6 structure + FULL-LINE coalesced state publish.
// Diagnosis r7: round chain is store-side (2048 2-byte sc1 write-through
// stores per block per round = partial-line WT storm), not read-BW.
// Fix: permute state k-space so thread (m,nn) owns ADJACENT positions
// p = slot*32 + 2nn + {0,1} for its two neurons (nt=0,1):
//   position p holds neuron nu(p) = 32*(p>>5) + 16*(p&1) + ((p&31)>>1)
// Layout St[k_oct 256][m 16][j 16]  (j 0-7 = s, 8-15 = c), half units.
// Producer: ONE dword store for s (packed nt pair) + ONE for c at +16B;
// a wave's 32 dwords cover exactly 4 full 128B lines -> write-combined
// full-line WT, no RMW. Consumer A-frags unchanged in shape (s,c now share
// lines; 8 base ptrs x 4 offsets). Permutation absorbed into W/W2/Wr
// COLUMN loads at init (interleaved float4/half4 pairs). Wi/x untouched
// (input space). Flags: r6's proven agent-scope per-wave fabric.
// W2 precompute: r7's LDS-staged GEMM (kept).

typedef _Float16 half_t;
typedef _Float16 half4 __attribute__((ext_vector_type(4)));
typedef _Float16 half8 __attribute__((ext_vector_type(8)));
typedef float f32x4 __attribute__((ext_vector_type(4)));

#define NHID 2048
#define NOUT 64
#define ST_UNIT 65536   // halfs per (buf,rep): [256 k_oct][16 m][16 j]
#define N_ROUNDS 256

#define MFMA16(A, B, C) __builtin_amdgcn_mfma_f32_16x16x32_f16(A, B, C, 0, 0, 0)

// ws layout (bytes):
//   [0, 4096)      : flags uint[4][256]  ([rep][slot*4+wave], monotonic)
//   [1M, 1M+1.5M)  : St half[3 buf][4 rep][ST_UNIT]
//   [8M, 16M)      : WT16 half[2048][2048] (W^T f16, scratch for w2)
//   [16M, 24M)     : W2   half[2048][2048]

__device__ __forceinline__ half8 cvt8(float4 lo, float4 hi) {
  half8 h;
  h[0] = (half_t)lo.x; h[1] = (half_t)lo.y; h[2] = (half_t)lo.z; h[3] = (half_t)lo.w;
  h[4] = (half_t)hi.x; h[5] = (half_t)hi.y; h[6] = (half_t)hi.z; h[7] = (half_t)hi.w;
  return h;
}
// interleaved: h[2i] = lo[i] (nu=base+i), h[2i+1] = hi[i] (nu=base+16+i)
__device__ __forceinline__ half8 cvt8i(float4 lo, float4 hi) {
  half8 h;
  h[0] = (half_t)lo.x; h[1] = (half_t)hi.x; h[2] = (half_t)lo.y; h[3] = (half_t)hi.y;
  h[4] = (half_t)lo.z; h[5] = (half_t)hi.z; h[6] = (half_t)lo.w; h[7] = (half_t)hi.w;
  return h;
}
__device__ __forceinline__ half8 ilv4(half4 lo, half4 hi) {
  half8 h;
  h[0] = lo[0]; h[1] = hi[0]; h[2] = lo[1]; h[3] = hi[1];
  h[4] = lo[2]; h[5] = hi[2]; h[6] = lo[3]; h[7] = hi[3];
  return h;
}

__global__ void psrnn_init_kernel(unsigned* flags, uint4* st) {
  int g = blockIdx.x * blockDim.x + threadIdx.x;  // 16384 threads x 2 uint4
  uint4 one; one.x = 0x3C003C00u; one.y = 0x3C003C00u; one.z = 0x3C003C00u; one.w = 0x3C003C00u;
  uint4 zer; zer.x = 0; zer.y = 0; zer.z = 0; zer.w = 0;
#pragma unroll
  for (int rr = 0; rr < 2; ++rr) {
    const int gg = g + rr * 16384;        // buf0: s-halves (even uint4) = 1.0
    st[gg] = (gg & 1) ? zer : one;
  }
  if (g < 1024) flags[g] = 0;
}

// W (fp32 row-major) -> WT16 (f16, transposed)
__global__ __launch_bounds__(256) void psrnn_conv_kernel(
    const float* __restrict__ Wh, half_t* __restrict__ WT16) {
  __shared__ float tile[64][65];
  const int bi = blockIdx.x & 31, bj = blockIdx.x >> 5;
  const int rs = threadIdx.x >> 6, c = threadIdx.x & 63;
#pragma unroll
  for (int i = 0; i < 16; ++i) {
    const int row = rs * 16 + i;
    tile[row][c] = Wh[(size_t)(bi * 64 + row) * NHID + bj * 64 + c];
  }
  __syncthreads();
#pragma unroll
  for (int i = 0; i < 16; ++i) {
    const int row = rs * 16 + i;
    WT16[(size_t)(bj * 64 + row) * NHID + bi * 64 + c] = (half_t)tile[c][row];
  }
}

// W2 = f16( f16(W) @ f16(W) ), 128x128 tiles, B staged in LDS (r7-proven)
__global__ __launch_bounds__(256) void psrnn_w2_kernel(
    const float* __restrict__ Wh, const half_t* __restrict__ WT16,
    half_t* __restrict__ W2) {
  __shared__ half_t Bs[128][40];
  const int bi = blockIdx.x & 15, bj = blockIdx.x >> 4;
  const int tid = threadIdx.x, w = tid >> 6, lane = tid & 63;
  const int lm = lane & 15, kg = lane >> 4;
  const int brow = tid >> 2, bseg = tid & 3;

  f32x4 acc[2][8];
#pragma unroll
  for (int mt = 0; mt < 2; ++mt)
#pragma unroll
    for (int nt = 0; nt < 8; ++nt) acc[mt][nt] = (f32x4){0.f, 0.f, 0.f, 0.f};

  for (int c = 0; c < 64; ++c) {
    __syncthreads();
#pragma unroll
    for (int i = 0; i < 2; ++i) {
      const int row = brow + i * 64;
      *(half8*)&Bs[row][bseg * 8] =
          *(const half8*)(WT16 + (size_t)(bj * 128 + row) * NHID + c * 32 + bseg * 8);
    }
    __syncthreads();
    const float* pa0 = Wh + (size_t)(bi * 128 + w * 32 + lm) * NHID + c * 32 + kg * 8;
    const float* pa1 = pa0 + (size_t)16 * NHID;
    half8 a0 = cvt8(*(const float4*)pa0, *(const float4*)(pa0 + 4));
    half8 a1 = cvt8(*(const float4*)pa1, *(const float4*)(pa1 + 4));
#pragma unroll
    for (int nt = 0; nt < 8; ++nt) {
      half8 b = *(const half8*)&Bs[nt * 16 + lm][kg * 8];
      acc[0][nt] = MFMA16(a0, b, acc[0][nt]);
      acc[1][nt] = MFMA16(a1, b, acc[1][nt]);
    }
  }
#pragma unroll
  for (int mt = 0; mt < 2; ++mt)
#pragma unroll
    for (int nt = 0; nt < 8; ++nt)
#pragma unroll
      for (int r = 0; r < 4; ++r)
        W2[(size_t)(bi * 128 + w * 32 + mt * 16 + kg * 4 + r) * NHID +
           bj * 128 + nt * 16 + lm] = (half_t)acc[mt][nt][r];
}

__global__ __launch_bounds__(256, 1) void psrnn_main_kernel(
    const float* __restrict__ x,      // [512][64][64]
    const float* __restrict__ Wi_w,   // [2048][64]
    const float* __restrict__ Wi_b,   // [2048]
    const float* __restrict__ Wh_w,   // [2048][2048]
    const float* __restrict__ Av,     // [2048]
    const float* __restrict__ Om,     // [2048]
    const half_t* __restrict__ W2,    // [2048][2048] f16 (true col order)
    unsigned* __restrict__ flags,
    half_t* __restrict__ St)
{
  __shared__ float ybuf[2][4][2][2][16][18];  // [par][wave][arr(y1,y23)][nt][m][n]
  __shared__ float ubuf[2][2][2][16][18];     // [par][t'][nt][m][n]

  const int tid = threadIdx.x, w = tid >> 6, lane = tid & 63;
  const int lm = lane & 15, kg = lane >> 4;
  const int rep = blockIdx.x & 3, slot = blockIdx.x >> 2;
  const int n0 = slot * 32, b0 = rep * 16;
  const int tpar = w >> 1, ntu = w & 1;  // u-duty: wave -> (timestep, nt)

  // ---- W, W2 B-frags with permuted columns: k-position p = 512w+32c+kg*8+j
  //      holds neuron nu = (512w+32c) + kg*4 + (j>>1) + 16*(j&1)
  half8 wb[2][16], w2b[2][16];
#pragma unroll
  for (int nt = 0; nt < 2; ++nt)
#pragma unroll
    for (int c = 0; c < 16; ++c) {
      const size_t row = (size_t)(n0 + nt * 16 + lm);
      const float* p = Wh_w + row * NHID + (w * 512 + c * 32 + kg * 4);
      wb[nt][c] = cvt8i(*(const float4*)p, *(const float4*)(p + 16));
      const half_t* q = W2 + row * NHID + (w * 512 + c * 32 + kg * 4);
      w2b[nt][c] = ilv4(*(const half4*)q, *(const half4*)(q + 16));
    }
  half8 wi0, wi1;  // Wi: input space, NOT permuted
  {
    const float* p = Wi_w + (size_t)(n0 + ntu * 16 + lm) * 64 + kg * 8;
    wi0 = cvt8(*(const float4*)p, *(const float4*)(p + 4));
    wi1 = cvt8(*(const float4*)(p + 32), *(const float4*)(p + 36));
  }

  // ---- combiner constants: thread owns (batch m, neurons n0+nt*16+nn)
  const int m = tid >> 4, nn = tid & 15;
  float cA2[2], cOm2[2], cB2[2];
#pragma unroll
  for (int nt = 0; nt < 2; ++nt) {
    const int ng = n0 + nt * 16 + nn;
    cA2[nt] = Av[ng]; cOm2[nt] = Om[ng]; cB2[nt] = Wi_b[ng];
  }
  // publish offset (halfs): positions (slot*32+2nn, +1), j = (nn&3)*2
  const int offp = (slot * 4 + (nn >> 2)) * 256 + m * 16 + (nn & 3) * 2;
  float cpr[2];

  unsigned* const pollp = flags + rep * 256 + w * 64 + lane;  // 64 producer waves
  unsigned* const myf   = flags + rep * 256 + slot * 4 + w;

  // ---- preloop: u_0 (waves 0,1), publish c_0 to buf0, flag=1
  if (w < 2) {
    const float* xp = x + (size_t)(b0 + lm) * 64;
    float4 a0 = *(const float4*)(xp + kg * 8), a1 = *(const float4*)(xp + kg * 8 + 4);
    float4 a2 = *(const float4*)(xp + 32 + kg * 8), a3 = *(const float4*)(xp + 36 + kg * 8);
    f32x4 au = {0.f, 0.f, 0.f, 0.f};
    au = MFMA16(cvt8(a0, a1), wi0, au);
    au = MFMA16(cvt8(a2, a3), wi1, au);
#pragma unroll
    for (int r = 0; r < 4; ++r) ubuf[0][0][ntu][kg * 4 + r][lm] = au[r];
  }
  __syncthreads();
  {
#pragma unroll
    for (int nt = 0; nt < 2; ++nt) {
      const float u0 = ubuf[0][0][nt][m][nn] + cB2[nt];
      cpr[nt] = cA2[nt] * __cosf(cOm2[nt] * 1.0f + u0);
    }
    unsigned dc = (unsigned)__builtin_bit_cast(unsigned short, (half_t)cpr[0]) |
                  ((unsigned)__builtin_bit_cast(unsigned short, (half_t)cpr[1]) << 16);
    const half_t* cp = St + (size_t)rep * ST_UNIT + offp + 8;  // c halves
    asm volatile("global_store_dword %0, %1, off sc1" :: "v"(cp), "v"(dc) : "memory");
    asm volatile("s_waitcnt vmcnt(0)" ::: "memory");
    if (lane == 0)
      __hip_atomic_store(myf, 1u, __ATOMIC_RELAXED, __HIP_MEMORY_SCOPE_AGENT);
  }
  float4 xr0, xr1, xr2, xr3;
  {
    const float* xp = x + ((size_t)(1 + tpar) * 64 + b0 + lm) * 64;
    xr0 = *(const float4*)(xp + kg * 8);  xr1 = *(const float4*)(xp + kg * 8 + 4);
    xr2 = *(const float4*)(xp + 32 + kg * 8); xr3 = *(const float4*)(xp + 36 + kg * 8);
  }

  int bR = 0;
  for (int k = 0; k < N_ROUNDS; ++k) {
    const int bW = (bR == 2) ? 0 : bR + 1;
    const half_t* rB = St + (size_t)(bR * 4 + rep) * ST_UNIT;
    half_t* wB       = St + (size_t)(bW * 4 + rep) * ST_UNIT;
    const int par = k & 1;

    // ---- phase A: u for t1=2k+1 (waves 0,1) / t2=2k+2 (waves 2,3)
    {
      f32x4 au = {0.f, 0.f, 0.f, 0.f};
      au = MFMA16(cvt8(xr0, xr1), wi0, au);
      au = MFMA16(cvt8(xr2, xr3), wi1, au);
#pragma unroll
      for (int r = 0; r < 4; ++r) ubuf[par][tpar][ntu][kg * 4 + r][lm] = au[r];
    }

    // ---- phase B: tight-spin poll on the 64 producer waves of this K-slice
    {
      const unsigned tgt = (unsigned)(k + 1);
      unsigned v = __hip_atomic_load(pollp, __ATOMIC_RELAXED, __HIP_MEMORY_SCOPE_AGENT);
      while (!__all((int)(v >= tgt)))
        v = __hip_atomic_load(pollp, __ATOMIC_RELAXED, __HIP_MEMORY_SCOPE_AGENT);
    }

    // ---- phase C: (s,c) A-frags; 8 bases, 4 loads each (s@0,2048; c@16,2064)
    const half_t* pb0 = rB + (size_t)(64 * w + 0  + kg) * 256 + lm * 16;
    const half_t* pb1 = rB + (size_t)(64 * w + 8  + kg) * 256 + lm * 16;
    const half_t* pb2 = rB + (size_t)(64 * w + 16 + kg) * 256 + lm * 16;
    const half_t* pb3 = rB + (size_t)(64 * w + 24 + kg) * 256 + lm * 16;
    const half_t* pb4 = rB + (size_t)(64 * w + 32 + kg) * 256 + lm * 16;
    const half_t* pb5 = rB + (size_t)(64 * w + 40 + kg) * 256 + lm * 16;
    const half_t* pb6 = rB + (size_t)(64 * w + 48 + kg) * 256 + lm * 16;
    const half_t* pb7 = rB + (size_t)(64 * w + 56 + kg) * 256 + lm * 16;
    float4 Sr[16], Cr[16];
    asm volatile(
        "global_load_dwordx4 %0, %32, off sc1\n\t"
        "global_load_dwordx4 %1, %32, off offset:2048 sc1\n\t"
        "global_load_dwordx4 %16, %32, off offset:16 sc1\n\t"
        "global_load_dwordx4 %17, %32, off offset:2064 sc1\n\t"
        "global_load_dwordx4 %2, %33, off sc1\n\t"
        "global_load_dwordx4 %3, %33, off offset:2048 sc1\n\t"
        "global_load_dwordx4 %18, %33, off offset:16 sc1\n\t"
        "global_load_dwordx4 %19, %33, off offset:2064 sc1\n\t"
        "global_load_dwordx4 %4, %34, off sc1\n\t"
        "global_load_dwordx4 %5, %34, off offset:2048 sc1\n\t"
        "global_load_dwordx4 %20, %34, off offset:16 sc1\n\t"
        "global_load_dwordx4 %21, %34, off offset:2064 sc1\n\t"
        "global_load_dwordx4 %6, %35, off sc1\n\t"
        "global_load_dwordx4 %7, %35, off offset:2048 sc1\n\t"
        "global_load_dwordx4 %22, %35, off offset:16 sc1\n\t"
        "global_load_dwordx4 %23, %35, off offset:2064 sc1\n\t"
        "global_load_dwordx4 %8, %36, off sc1\n\t"
        "global_load_dwordx4 %9, %36, off offset:2048 sc1\n\t"
        "global_load_dwordx4 %24, %36, off offset:16 sc1\n\t"
        "global_load_dwordx4 %25, %36, off offset:2064 sc1\n\t"
        "global_load_dwordx4 %10, %37, off sc1\n\t"
        "global_load_dwordx4 %11, %37, off offset:2048 sc1\n\t"
        "global_load_dwordx4 %26, %37, off offset:16 sc1\n\t"
        "global_load_dwordx4 %27, %37, off offset:2064 sc1\n\t"
        "global_load_dwordx4 %12, %38, off sc1\n\t"
        "global_load_dwordx4 %13, %38, off offset:2048 sc1\n\t"
        "global_load_dwordx4 %28, %38, off offset:16 sc1\n\t"
        "global_load_dwordx4 %29, %38, off offset:2064 sc1\n\t"
        "global_load_dwordx4 %14, %39, off sc1\n\t"
        "global_load_dwordx4 %15, %39, off offset:2048 sc1\n\t"
        "global_load_dwordx4 %30, %39, off offset:16 sc1\n\t"
        "global_load_dwordx4 %31, %39, off offset:2064 sc1\n\t"
        "s_waitcnt vmcnt(0)"
        : "=&v"(Sr[0]), "=&v"(Sr[1]), "=&v"(Sr[2]), "=&v"(Sr[3]),
          "=&v"(Sr[4]), "=&v"(Sr[5]), "=&v"(Sr[6]), "=&v"(Sr[7]),
          "=&v"(Sr[8]), "=&v"(Sr[9]), "=&v"(Sr[10]), "=&v"(Sr[11]),
          "=&v"(Sr[12]), "=&v"(Sr[13]), "=&v"(Sr[14]), "=&v"(Sr[15]),
          "=&v"(Cr[0]), "=&v"(Cr[1]), "=&v"(Cr[2]), "=&v"(Cr[3]),
          "=&v"(Cr[4]), "=&v"(Cr[5]), "=&v"(Cr[6]), "=&v"(Cr[7]),
          "=&v"(Cr[8]), "=&v"(Cr[9]), "=&v"(Cr[10]), "=&v"(Cr[11]),
          "=&v"(Cr[12]), "=&v"(Cr[13]), "=&v"(Cr[14]), "=&v"(Cr[15])
        : "v"(pb0), "v"(pb1), "v"(pb2), "v"(pb3),
          "v"(pb4), "v"(pb5), "v"(pb6), "v"(pb7)
        : "memory");

    // ---- phase D: y1 = W*s ; y23 = W*c + W^2*s   (96 MFMA)
    f32x4 y1a0 = {0.f,0.f,0.f,0.f}, y1a1 = {0.f,0.f,0.f,0.f};
    f32x4 y23a0 = {0.f,0.f,0.f,0.f}, y23a1 = {0.f,0.f,0.f,0.f};
#pragma unroll
    for (int c = 0; c < 16; ++c) {
      half8 sf = __builtin_bit_cast(half8, Sr[c]);
      half8 cf = __builtin_bit_cast(half8, Cr[c]);
      y1a0 = MFMA16(sf, wb[0][c], y1a0);
      y1a1 = MFMA16(sf, wb[1][c], y1a1);
      y23a0 = MFMA16(cf, wb[0][c], y23a0);
      y23a1 = MFMA16(cf, wb[1][c], y23a1);
      y23a0 = MFMA16(sf, w2b[0][c], y23a0);
      y23a1 = MFMA16(sf, w2b[1][c], y23a1);
    }
#pragma unroll
    for (int r = 0; r < 4; ++r) {
      ybuf[par][w][0][0][kg * 4 + r][lm] = y1a0[r];
      ybuf[par][w][0][1][kg * 4 + r][lm] = y1a1[r];
      ybuf[par][w][1][0][kg * 4 + r][lm] = y23a0[r];
      ybuf[par][w][1][1][kg * 4 + r][lm] = y23a1[r];
    }
    __syncthreads();  // the only barrier per round

    // ---- phase E: combine two steps; publish as 2 coalesced dwords; flag
    float s2v[2], c2v[2];
#pragma unroll
    for (int nt = 0; nt < 2; ++nt) {
      const float y1v = ybuf[par][0][0][nt][m][nn] + ybuf[par][1][0][nt][m][nn] +
                        ybuf[par][2][0][nt][m][nn] + ybuf[par][3][0][nt][m][nn];
      const float y23v = ybuf[par][0][1][nt][m][nn] + ybuf[par][1][1][nt][m][nn] +
                         ybuf[par][2][1][nt][m][nn] + ybuf[par][3][1][nt][m][nn];
      const float u1 = ubuf[par][0][nt][m][nn] + cB2[nt];
      const float u2 = ubuf[par][1][nt][m][nn] + cB2[nt];
      const float s1 = cpr[nt] + y1v;
      const float c1 = cA2[nt] * __cosf(cOm2[nt] * s1 + u1);
      const float s2 = c1 + y23v;
      const float c2 = cA2[nt] * __cosf(cOm2[nt] * s2 + u2);
      cpr[nt] = c2; s2v[nt] = s2; c2v[nt] = c2;
    }
    {
      unsigned ds = (unsigned)__builtin_bit_cast(unsigned short, (half_t)s2v[0]) |
                    ((unsigned)__builtin_bit_cast(unsigned short, (half_t)s2v[1]) << 16);
      unsigned dc = (unsigned)__builtin_bit_cast(unsigned short, (half_t)c2v[0]) |
                    ((unsigned)__builtin_bit_cast(unsigned short, (half_t)c2v[1]) << 16);
      const half_t* sp = wB + offp;
      asm volatile(
          "global_store_dword %0, %1, off sc1\n\t"
          "global_store_dword %0, %2, off offset:16 sc1"
          :: "v"(sp), "v"(ds), "v"(dc) : "memory");
    }
    asm volatile("s_waitcnt vmcnt(0)" ::: "memory");  // wave's stores at LLC
    if (lane == 0)
      __hip_atomic_store(myf, (unsigned)(k + 2), __ATOMIC_RELAXED, __HIP_MEMORY_SCOPE_AGENT);

    // ---- phase G: x prefetch for round k+1 (off the serial chain)
    {
      int t = 2 * k + 3 + tpar;
      if (t > 511) t = 511;
      const float* xp = x + ((size_t)t * 64 + b0 + lm) * 64;
      xr0 = *(const float4*)(xp + kg * 8);  xr1 = *(const float4*)(xp + kg * 8 + 4);
      xr2 = *(const float4*)(xp + 32 + kg * 8); xr3 = *(const float4*)(xp + 36 + kg * 8);
    }
    bR = bW;
  }
}

__global__ __launch_bounds__(256) void psrnn_readout_kernel(
    const float* __restrict__ Wr_w,   // [64][2048]
    const float* __restrict__ Wr_b,   // [64]
    const half_t* __restrict__ St,    // base; final state = buf 1
    float* __restrict__ out)          // [64][64]
{
  const int tid = threadIdx.x, v = tid >> 6, lane = tid & 63;
  const int lm = lane & 15, kg = lane >> 4;
  const int rep = blockIdx.x;  // 4 blocks
  const half_t* sb = St + (size_t)(1 * 4 + rep) * ST_UNIT;  // buf (255+1)%3 = 1

  f32x4 acc = {0.f, 0.f, 0.f, 0.f};
  for (int cg = 0; cg < 64; ++cg) {
    half8 a = *(const half8*)(sb + (size_t)(cg * 4 + kg) * 256 + lm * 16);  // s halves
    const float* p = Wr_w + (size_t)(v * 16 + lm) * NHID + cg * 32 + kg * 4;
    half8 b = cvt8i(*(const float4*)p, *(const float4*)(p + 16));  // permuted cols
    acc = MFMA16(a, b, acc);
  }
#pragma unroll
  for (int r = 0; r < 4; ++r) {
    const int bidx = rep * 16 + kg * 4 + r;
    out[bidx * NOUT + v * 16 + lm] = acc[r] + Wr_b[v * 16 + lm];
  }
}

extern "C" void kernel_launch(void* const* d_in, const int* in_sizes, int n_in,
                              void* d_out, int out_size, void* d_ws, size_t ws_size,
                              hipStream_t stream) {
  const float* x    = (const float*)d_in[0];
  const float* Wi_w = (const float*)d_in[1];
  const float* Wi_b = (const float*)d_in[2];
  const float* Wh_w = (const float*)d_in[3];
  const float* Av   = (const float*)d_in[4];
  const float* Om   = (const float*)d_in[5];
  const float* Wr_w = (const float*)d_in[6];
  const float* Wr_b = (const float*)d_in[7];

  unsigned* flags = (unsigned*)d_ws;
  half_t*   St    = (half_t*)((char*)d_ws + (1u << 20));
  half_t*   WT16  = (half_t*)((char*)d_ws + (8u << 20));
  half_t*   W2    = (half_t*)((char*)d_ws + (16u << 20));

  psrnn_conv_kernel<<<1024, 256, 0, stream>>>(Wh_w, WT16);
  psrnn_w2_kernel<<<256, 256, 0, stream>>>(Wh_w, WT16, W2);
  psrnn_init_kernel<<<64, 256, 0, stream>>>(flags, (uint4*)St);
  psrnn_main_kernel<<<256, 256, 0, stream>>>(x, Wi_w, Wi_b, Wh_w, Av, Om, W2, flags, St);
  psrnn_readout_kernel<<<4, 256, 0, stream>>>(Wr_w, Wr_b, St, (float*)d_out);
}